// Round 2
// baseline (283.445 us; speedup 1.0000x reference)
//
#include <hip/hip_runtime.h>
#include <hip/hip_bf16.h>
#include <stdint.h>
#include <math.h>

#define B_DIM 32
#define T_DIM 1024
#define C_DIM 768
#define NTILE 8                 // T_DIM / 128
#define NTRI  36                // NTILE*(NTILE+1)/2

typedef __bf16 bf16x8 __attribute__((ext_vector_type(8)));
typedef float f32x4 __attribute__((ext_vector_type(4)));

typedef __attribute__((address_space(1))) void gvoid_t;
typedef __attribute__((address_space(3))) void lvoid_t;

__device__ __forceinline__ unsigned short f32_to_bf16_rne(float f) {
    union { float f; uint32_t u; } v; v.f = f;
    uint32_t u = v.u;
    uint32_t r = 0x7fffu + ((u >> 16) & 1u);
    return (unsigned short)((u + r) >> 16);
}

// One wave per row: compute 1/||x||_2 and store normalized row as bf16.
__global__ __launch_bounds__(256) void normalize_rows(const float* __restrict__ x,
                                                      unsigned short* __restrict__ m) {
    const int row  = blockIdx.x * 4 + (threadIdx.x >> 6);
    const int lane = threadIdx.x & 63;
    const float4* xr = (const float4*)(x + (size_t)row * C_DIM);
    float4 v0 = xr[lane];
    float4 v1 = xr[lane + 64];
    float4 v2 = xr[lane + 128];
    float ss = v0.x*v0.x + v0.y*v0.y + v0.z*v0.z + v0.w*v0.w
             + v1.x*v1.x + v1.y*v1.y + v1.z*v1.z + v1.w*v1.w
             + v2.x*v2.x + v2.y*v2.y + v2.z*v2.z + v2.w*v2.w;
    #pragma unroll
    for (int off = 32; off > 0; off >>= 1)
        ss += __shfl_xor(ss, off, 64);
    const float rs = rsqrtf(ss);
    ushort4* mr = (ushort4*)(m + (size_t)row * C_DIM);
    ushort4 o;
    o.x = f32_to_bf16_rne(v0.x * rs); o.y = f32_to_bf16_rne(v0.y * rs);
    o.z = f32_to_bf16_rne(v0.z * rs); o.w = f32_to_bf16_rne(v0.w * rs);
    mr[lane] = o;
    o.x = f32_to_bf16_rne(v1.x * rs); o.y = f32_to_bf16_rne(v1.y * rs);
    o.z = f32_to_bf16_rne(v1.z * rs); o.w = f32_to_bf16_rne(v1.w * rs);
    mr[lane + 64] = o;
    o.x = f32_to_bf16_rne(v2.x * rs); o.y = f32_to_bf16_rne(v2.y * rs);
    o.z = f32_to_bf16_rne(v2.z * rs); o.w = f32_to_bf16_rne(v2.w * rs);
    mr[lane + 128] = o;
}

// Batched symmetric NT GEMM: out[b,i,j] = 1 - sum_k M[b,i,k]*M[b,j,k].
// Only upper-triangular 128x128 tiles (ti <= tj) computed; off-diagonal
// tiles are mirrored with a transposed f32x4 store. 4 waves per block,
// each wave a 4x4 grid of 16x16x32 bf16 MFMAs.
__global__ __launch_bounds__(256) void gemm_nt_sym(const unsigned short* __restrict__ M,
                                                   float* __restrict__ out) {
    __shared__ unsigned short As[128 * 32];
    __shared__ unsigned short Bs[128 * 32];

    const int b   = blockIdx.y;
    const int idx = blockIdx.x;                 // triangular tile index, 0..35
    // idx = tj*(tj+1)/2 + ti, ti <= tj
    int tj = (int)((sqrtf(8.0f * (float)idx + 1.0f) - 1.0f) * 0.5f);
    if (tj * (tj + 1) / 2 > idx) --tj;          // guard float rounding
    const int ti = idx - tj * (tj + 1) / 2;

    const int tid  = threadIdx.x;
    const int wave = tid >> 6;
    const int lane = tid & 63;
    const int quad = lane >> 4;
    const int l16  = lane & 15;
    const int wi = wave >> 1;
    const int wj = wave & 1;

    const unsigned short* Mb = M + (size_t)b * T_DIM * C_DIM;

    // Staging: tile [128][32] bf16 row-major = 8 KB. Wave w stages chunks 2w,
    // 2w+1 (1 KB each, 64 lanes x 16 B). LDS dest = wave-uniform base + lane*16.
    const int srow0 = (wave * 2 + 0) * 16 + (lane >> 2);
    const int srow1 = (wave * 2 + 1) * 16 + (lane >> 2);
    const int scol  = (lane & 3) * 8;

    const unsigned short* gA0 = Mb + (size_t)(ti * 128 + srow0) * C_DIM + scol;
    const unsigned short* gA1 = Mb + (size_t)(ti * 128 + srow1) * C_DIM + scol;
    const unsigned short* gB0 = Mb + (size_t)(tj * 128 + srow0) * C_DIM + scol;
    const unsigned short* gB1 = Mb + (size_t)(tj * 128 + srow1) * C_DIM + scol;

    unsigned short* lA0 = &As[(wave * 2 + 0) * 512];
    unsigned short* lA1 = &As[(wave * 2 + 1) * 512];
    unsigned short* lB0 = &Bs[(wave * 2 + 0) * 512];
    unsigned short* lB1 = &Bs[(wave * 2 + 1) * 512];

    f32x4 acc[4][4];
    #pragma unroll
    for (int i = 0; i < 4; ++i)
        #pragma unroll
        for (int j = 0; j < 4; ++j)
            acc[i][j] = (f32x4){0.f, 0.f, 0.f, 0.f};

    for (int k0 = 0; k0 < C_DIM; k0 += 32) {
        __builtin_amdgcn_global_load_lds((gvoid_t*)(gA0 + k0), (lvoid_t*)lA0, 16, 0, 0);
        __builtin_amdgcn_global_load_lds((gvoid_t*)(gA1 + k0), (lvoid_t*)lA1, 16, 0, 0);
        __builtin_amdgcn_global_load_lds((gvoid_t*)(gB0 + k0), (lvoid_t*)lB0, 16, 0, 0);
        __builtin_amdgcn_global_load_lds((gvoid_t*)(gB1 + k0), (lvoid_t*)lB1, 16, 0, 0);
        __syncthreads();

        bf16x8 af[4], bfr[4];
        #pragma unroll
        for (int ii = 0; ii < 4; ++ii) {
            af[ii]  = *(const bf16x8*)&As[(wi * 64 + ii * 16 + l16) * 32 + quad * 8];
            bfr[ii] = *(const bf16x8*)&Bs[(wj * 64 + ii * 16 + l16) * 32 + quad * 8];
        }
        #pragma unroll
        for (int ii = 0; ii < 4; ++ii)
            #pragma unroll
            for (int jj = 0; jj < 4; ++jj)
                acc[ii][jj] = __builtin_amdgcn_mfma_f32_16x16x32_bf16(af[ii], bfr[jj], acc[ii][jj], 0, 0, 0);
        __syncthreads();
    }

    // Epilogue. C/D layout: col = lane&15, row = quad*4 + reg. out = 1 - acc.
    float* outb = out + (size_t)b * T_DIM * T_DIM;
    #pragma unroll
    for (int ii = 0; ii < 4; ++ii) {
        const int rowbase = ti * 128 + wi * 64 + ii * 16 + quad * 4;
        #pragma unroll
        for (int jj = 0; jj < 4; ++jj) {
            const int col = tj * 128 + wj * 64 + jj * 16 + l16;
            #pragma unroll
            for (int r = 0; r < 4; ++r)
                outb[(size_t)(rowbase + r) * T_DIM + col] = 1.0f - acc[ii][jj][r];
        }
    }
    if (ti != tj) {
        // Mirror tile: out[col][row] = out[row][col]. Each lane's 4 acc values
        // share one col and 4 consecutive rows -> one aligned f32x4 store.
        #pragma unroll
        for (int ii = 0; ii < 4; ++ii) {
            const int rowbase = ti * 128 + wi * 64 + ii * 16 + quad * 4;
            #pragma unroll
            for (int jj = 0; jj < 4; ++jj) {
                const int col = tj * 128 + wj * 64 + jj * 16 + l16;
                f32x4 v;
                v[0] = 1.0f - acc[ii][jj][0];
                v[1] = 1.0f - acc[ii][jj][1];
                v[2] = 1.0f - acc[ii][jj][2];
                v[3] = 1.0f - acc[ii][jj][3];
                *(f32x4*)(outb + (size_t)col * T_DIM + rowbase) = v;
            }
        }
    }
}

extern "C" void kernel_launch(void* const* d_in, const int* in_sizes, int n_in,
                              void* d_out, int out_size, void* d_ws, size_t ws_size,
                              hipStream_t stream) {
    const float* x = (const float*)d_in[0];
    float* out = (float*)d_out;
    unsigned short* metric = (unsigned short*)d_ws;  // 32768 x 768 bf16 = 48 MiB

    normalize_rows<<<dim3((B_DIM * T_DIM) / 4), dim3(256), 0, stream>>>(x, metric);
    // 36 upper-triangular tiles per batch, 32 batches = 1152 blocks.
    gemm_nt_sym<<<dim3(NTRI, B_DIM), dim3(256), 0, stream>>>(metric, out);
}

// Round 3
// 260.223 us; speedup vs baseline: 1.0892x; 1.0892x over previous
//
#include <hip/hip_runtime.h>
#include <hip/hip_bf16.h>
#include <stdint.h>
#include <math.h>

#define B_DIM 32
#define T_DIM 1024
#define C_DIM 768
#define NTILE 8                 // T_DIM / 128
#define NTRI  36                // NTILE*(NTILE+1)/2
#define KITER (C_DIM / 32)      // 24

typedef __bf16 bf16x8 __attribute__((ext_vector_type(8)));
typedef float f32x4 __attribute__((ext_vector_type(4)));

typedef __attribute__((address_space(1))) void gvoid_t;
typedef __attribute__((address_space(3))) void lvoid_t;

__device__ __forceinline__ unsigned short f32_to_bf16_rne(float f) {
    union { float f; uint32_t u; } v; v.f = f;
    uint32_t u = v.u;
    uint32_t r = 0x7fffu + ((u >> 16) & 1u);
    return (unsigned short)((u + r) >> 16);
}

// One wave per row: compute 1/||x||_2 and store normalized row as bf16.
__global__ __launch_bounds__(256) void normalize_rows(const float* __restrict__ x,
                                                      unsigned short* __restrict__ m) {
    const int row  = blockIdx.x * 4 + (threadIdx.x >> 6);
    const int lane = threadIdx.x & 63;
    const float4* xr = (const float4*)(x + (size_t)row * C_DIM);
    float4 v0 = xr[lane];
    float4 v1 = xr[lane + 64];
    float4 v2 = xr[lane + 128];
    float ss = v0.x*v0.x + v0.y*v0.y + v0.z*v0.z + v0.w*v0.w
             + v1.x*v1.x + v1.y*v1.y + v1.z*v1.z + v1.w*v1.w
             + v2.x*v2.x + v2.y*v2.y + v2.z*v2.z + v2.w*v2.w;
    #pragma unroll
    for (int off = 32; off > 0; off >>= 1)
        ss += __shfl_xor(ss, off, 64);
    const float rs = rsqrtf(ss);
    ushort4* mr = (ushort4*)(m + (size_t)row * C_DIM);
    ushort4 o;
    o.x = f32_to_bf16_rne(v0.x * rs); o.y = f32_to_bf16_rne(v0.y * rs);
    o.z = f32_to_bf16_rne(v0.z * rs); o.w = f32_to_bf16_rne(v0.w * rs);
    mr[lane] = o;
    o.x = f32_to_bf16_rne(v1.x * rs); o.y = f32_to_bf16_rne(v1.y * rs);
    o.z = f32_to_bf16_rne(v1.z * rs); o.w = f32_to_bf16_rne(v1.w * rs);
    mr[lane + 64] = o;
    o.x = f32_to_bf16_rne(v2.x * rs); o.y = f32_to_bf16_rne(v2.y * rs);
    o.z = f32_to_bf16_rne(v2.z * rs); o.w = f32_to_bf16_rne(v2.w * rs);
    mr[lane + 128] = o;
}

// Batched symmetric NT GEMM: out[b,i,j] = 1 - sum_k M[b,i,k]*M[b,j,k].
// Upper-triangular 128x128 tiles only; off-diagonal mirrored via transposed
// f32x4 stores. Grid flattened with batch-fastest order so all 36 blocks of
// a batch land on one XCD (round-robin dispatch): b = blockIdx.x & 31.
// K-loop: single-barrier double-buffered LDS — stage(next) issued right
// after the barrier, drained by the NEXT barrier's vmcnt(0), so the DMA
// overlaps the whole compute phase.
__global__ __launch_bounds__(256) void gemm_nt_sym(const unsigned short* __restrict__ M,
                                                   float* __restrict__ out) {
    __shared__ unsigned short As[2][128 * 32];
    __shared__ unsigned short Bs[2][128 * 32];

    const int b   = blockIdx.x & 31;   // batch fastest -> batch pinned to XCD (b&7)
    const int idx = blockIdx.x >> 5;   // triangular tile index, 0..35
    int tj = (int)((sqrtf(8.0f * (float)idx + 1.0f) - 1.0f) * 0.5f);
    if (tj * (tj + 1) / 2 > idx) --tj;
    const int ti = idx - tj * (tj + 1) / 2;

    const int tid  = threadIdx.x;
    const int wave = tid >> 6;
    const int lane = tid & 63;
    const int quad = lane >> 4;
    const int l16  = lane & 15;
    const int wi = wave >> 1;
    const int wj = wave & 1;

    const unsigned short* Mb = M + (size_t)b * T_DIM * C_DIM;

    // Staging: tile [128][32] bf16 row-major = 8 KB. Wave w stages chunks 2w,
    // 2w+1 (1 KB each, 64 lanes x 16 B). LDS dest = wave-uniform base + lane*16.
    const int srow0 = (wave * 2 + 0) * 16 + (lane >> 2);
    const int srow1 = (wave * 2 + 1) * 16 + (lane >> 2);
    const int scol  = (lane & 3) * 8;

    const unsigned short* gA0 = Mb + (size_t)(ti * 128 + srow0) * C_DIM + scol;
    const unsigned short* gA1 = Mb + (size_t)(ti * 128 + srow1) * C_DIM + scol;
    const unsigned short* gB0 = Mb + (size_t)(tj * 128 + srow0) * C_DIM + scol;
    const unsigned short* gB1 = Mb + (size_t)(tj * 128 + srow1) * C_DIM + scol;

    const int c0 = (wave * 2 + 0) * 512;
    const int c1 = (wave * 2 + 1) * 512;

    f32x4 acc[4][4];
    #pragma unroll
    for (int i = 0; i < 4; ++i)
        #pragma unroll
        for (int j = 0; j < 4; ++j)
            acc[i][j] = (f32x4){0.f, 0.f, 0.f, 0.f};

    // Prologue: stage K-slice 0 into buffer 0.
    __builtin_amdgcn_global_load_lds((gvoid_t*)gA0, (lvoid_t*)&As[0][c0], 16, 0, 0);
    __builtin_amdgcn_global_load_lds((gvoid_t*)gA1, (lvoid_t*)&As[0][c1], 16, 0, 0);
    __builtin_amdgcn_global_load_lds((gvoid_t*)gB0, (lvoid_t*)&Bs[0][c0], 16, 0, 0);
    __builtin_amdgcn_global_load_lds((gvoid_t*)gB1, (lvoid_t*)&Bs[0][c1], 16, 0, 0);

    for (int it = 0; it < KITER; ++it) {
        const int cur = it & 1;
        // Drains this wave's outstanding stage loads (vmcnt(0) before barrier)
        // and guarantees everyone finished reading buf[cur^1] from iter it-1.
        __syncthreads();
        if (it + 1 < KITER) {
            const int k0 = (it + 1) * 32;
            const int nxt = cur ^ 1;
            __builtin_amdgcn_global_load_lds((gvoid_t*)(gA0 + k0), (lvoid_t*)&As[nxt][c0], 16, 0, 0);
            __builtin_amdgcn_global_load_lds((gvoid_t*)(gA1 + k0), (lvoid_t*)&As[nxt][c1], 16, 0, 0);
            __builtin_amdgcn_global_load_lds((gvoid_t*)(gB0 + k0), (lvoid_t*)&Bs[nxt][c0], 16, 0, 0);
            __builtin_amdgcn_global_load_lds((gvoid_t*)(gB1 + k0), (lvoid_t*)&Bs[nxt][c1], 16, 0, 0);
        }

        bf16x8 af[4], bfr[4];
        #pragma unroll
        for (int ii = 0; ii < 4; ++ii) {
            af[ii]  = *(const bf16x8*)&As[cur][(wi * 64 + ii * 16 + l16) * 32 + quad * 8];
            bfr[ii] = *(const bf16x8*)&Bs[cur][(wj * 64 + ii * 16 + l16) * 32 + quad * 8];
        }
        #pragma unroll
        for (int ii = 0; ii < 4; ++ii)
            #pragma unroll
            for (int jj = 0; jj < 4; ++jj)
                acc[ii][jj] = __builtin_amdgcn_mfma_f32_16x16x32_bf16(af[ii], bfr[jj], acc[ii][jj], 0, 0, 0);
    }

    // Epilogue. C/D layout: col = lane&15, row = quad*4 + reg. out = 1 - acc.
    float* outb = out + (size_t)b * T_DIM * T_DIM;
    #pragma unroll
    for (int ii = 0; ii < 4; ++ii) {
        const int rowbase = ti * 128 + wi * 64 + ii * 16 + quad * 4;
        #pragma unroll
        for (int jj = 0; jj < 4; ++jj) {
            const int col = tj * 128 + wj * 64 + jj * 16 + l16;
            #pragma unroll
            for (int r = 0; r < 4; ++r)
                outb[(size_t)(rowbase + r) * T_DIM + col] = 1.0f - acc[ii][jj][r];
        }
    }
    if (ti != tj) {
        // Mirror tile: each lane's 4 acc values share one col and 4 consecutive
        // rows -> one aligned f32x4 store; 4 quads of same l16 cover a 64B line.
        #pragma unroll
        for (int ii = 0; ii < 4; ++ii) {
            const int rowbase = ti * 128 + wi * 64 + ii * 16 + quad * 4;
            #pragma unroll
            for (int jj = 0; jj < 4; ++jj) {
                const int col = tj * 128 + wj * 64 + jj * 16 + l16;
                f32x4 v;
                v[0] = 1.0f - acc[ii][jj][0];
                v[1] = 1.0f - acc[ii][jj][1];
                v[2] = 1.0f - acc[ii][jj][2];
                v[3] = 1.0f - acc[ii][jj][3];
                *(f32x4*)(outb + (size_t)col * T_DIM + rowbase) = v;
            }
        }
    }
}

extern "C" void kernel_launch(void* const* d_in, const int* in_sizes, int n_in,
                              void* d_out, int out_size, void* d_ws, size_t ws_size,
                              hipStream_t stream) {
    const float* x = (const float*)d_in[0];
    float* out = (float*)d_out;
    unsigned short* metric = (unsigned short*)d_ws;  // 32768 x 768 bf16 = 48 MiB

    normalize_rows<<<dim3((B_DIM * T_DIM) / 4), dim3(256), 0, stream>>>(x, metric);
    // 1152 blocks, batch-fastest: all 36 tiles of batch b share XCD (b&7).
    gemm_nt_sym<<<dim3(NTRI * B_DIM), dim3(256), 0, stream>>>(metric, out);
}

// Round 4
// 252.064 us; speedup vs baseline: 1.1245x; 1.0324x over previous
//
#include <hip/hip_runtime.h>
#include <hip/hip_bf16.h>
#include <stdint.h>
#include <math.h>

#define B_DIM 32
#define T_DIM 1024
#define C_DIM 768
#define NTILE 8                 // T_DIM / 128
#define NTRI  36                // NTILE*(NTILE+1)/2
#define KITER (C_DIM / 32)      // 24

typedef float f32x4 __attribute__((ext_vector_type(4)));

typedef __attribute__((address_space(1))) void gvoid_t;
typedef __attribute__((address_space(3))) void lvoid_t;

// One wave per row: compute 1/||x||_2 and store normalized row as fp8 e4m3.
// Row layout: 768 fp8 bytes = 192 dwords; lane L owns dword L, L+64, L+128
// (elements 4L..4L+3 etc.) -> coalesced dword stores.
__global__ __launch_bounds__(256) void normalize_rows_fp8(const float* __restrict__ x,
                                                          uint32_t* __restrict__ m) {
    const int row  = blockIdx.x * 4 + (threadIdx.x >> 6);
    const int lane = threadIdx.x & 63;
    const float4* xr = (const float4*)(x + (size_t)row * C_DIM);
    float4 v0 = xr[lane];
    float4 v1 = xr[lane + 64];
    float4 v2 = xr[lane + 128];
    float ss = v0.x*v0.x + v0.y*v0.y + v0.z*v0.z + v0.w*v0.w
             + v1.x*v1.x + v1.y*v1.y + v1.z*v1.z + v1.w*v1.w
             + v2.x*v2.x + v2.y*v2.y + v2.z*v2.z + v2.w*v2.w;
    #pragma unroll
    for (int off = 32; off > 0; off >>= 1)
        ss += __shfl_xor(ss, off, 64);
    const float rs = rsqrtf(ss);
    uint32_t* mr = m + (size_t)row * (C_DIM / 4);
    int p;
    p = __builtin_amdgcn_cvt_pk_fp8_f32(v0.x * rs, v0.y * rs, 0, false);
    p = __builtin_amdgcn_cvt_pk_fp8_f32(v0.z * rs, v0.w * rs, p, true);
    mr[lane] = (uint32_t)p;
    p = __builtin_amdgcn_cvt_pk_fp8_f32(v1.x * rs, v1.y * rs, 0, false);
    p = __builtin_amdgcn_cvt_pk_fp8_f32(v1.z * rs, v1.w * rs, p, true);
    mr[lane + 64] = (uint32_t)p;
    p = __builtin_amdgcn_cvt_pk_fp8_f32(v2.x * rs, v2.y * rs, 0, false);
    p = __builtin_amdgcn_cvt_pk_fp8_f32(v2.z * rs, v2.w * rs, p, true);
    mr[lane + 128] = (uint32_t)p;
}

// Batched symmetric NT GEMM on fp8 e4m3: out[b,i,j] = 1 - sum_k M[b,i,k]*M[b,j,k].
// Upper-triangular 128x128 tiles only; off-diagonal mirrored via transposed
// f32x4 stores. Batch-fastest flat grid pins each batch's 36 blocks to one XCD.
// K-loop: single-barrier LDS double-buffer — stage(next) issued right after the
// barrier, drained by the NEXT barrier's vmcnt(0), overlapping all of compute.
__global__ __launch_bounds__(256) void gemm_nt_sym_fp8(const uint8_t* __restrict__ M,
                                                       float* __restrict__ out) {
    // Tile [128][32] fp8 = 4 KB per matrix per buffer (16 KB total).
    __shared__ uint8_t As[2][128 * 32];
    __shared__ uint8_t Bs[2][128 * 32];

    const int b   = blockIdx.x & 31;   // batch fastest -> batch pinned to XCD (b&7)
    const int idx = blockIdx.x >> 5;   // triangular tile index, 0..35
    int tj = (int)((sqrtf(8.0f * (float)idx + 1.0f) - 1.0f) * 0.5f);
    if (tj * (tj + 1) / 2 > idx) --tj;
    const int ti = idx - tj * (tj + 1) / 2;

    const int tid  = threadIdx.x;
    const int wave = tid >> 6;
    const int lane = tid & 63;
    const int quad = lane >> 4;
    const int l16  = lane & 15;
    const int wi = wave >> 1;
    const int wj = wave & 1;

    const uint8_t* Mb = M + (size_t)b * T_DIM * C_DIM;

    // Staging: tile = 4 chunks of 1 KB; wave w stages chunk w of A and of B.
    // Chunk rows: w*32 .. w*32+31 (32 B/row, 2 lanes per row).
    // LDS dest = wave-uniform chunk base + lane*16 (HW rule).
    const int srow = wave * 32 + (lane >> 1);
    const int scol = (lane & 1) * 16;

    const uint8_t* gA = Mb + (size_t)(ti * 128 + srow) * C_DIM + scol;
    const uint8_t* gB = Mb + (size_t)(tj * 128 + srow) * C_DIM + scol;
    const int cbase = wave * 1024;

    f32x4 acc[4][4];
    #pragma unroll
    for (int i = 0; i < 4; ++i)
        #pragma unroll
        for (int j = 0; j < 4; ++j)
            acc[i][j] = (f32x4){0.f, 0.f, 0.f, 0.f};

    // Prologue: stage K-slice 0 into buffer 0.
    __builtin_amdgcn_global_load_lds((gvoid_t*)gA, (lvoid_t*)&As[0][cbase], 16, 0, 0);
    __builtin_amdgcn_global_load_lds((gvoid_t*)gB, (lvoid_t*)&Bs[0][cbase], 16, 0, 0);

    for (int it = 0; it < KITER; ++it) {
        const int cur = it & 1;
        // Drains this wave's outstanding stage DMA (vmcnt(0) before barrier) and
        // guarantees all waves finished reading buf[cur^1] from iter it-1.
        __syncthreads();
        if (it + 1 < KITER) {
            const int k0 = (it + 1) * 32;   // byte offset along K
            const int nxt = cur ^ 1;
            __builtin_amdgcn_global_load_lds((gvoid_t*)(gA + k0), (lvoid_t*)&As[nxt][cbase], 16, 0, 0);
            __builtin_amdgcn_global_load_lds((gvoid_t*)(gB + k0), (lvoid_t*)&Bs[nxt][cbase], 16, 0, 0);
        }

        // Fragments: lane (l16, quad) reads 8 fp8 at row (w*64 + ii*16 + l16),
        // cols quad*8..quad*8+7 -> aligned ds_read_b64.
        long af[4], bfr[4];
        #pragma unroll
        for (int ii = 0; ii < 4; ++ii) {
            af[ii]  = *(const long*)&As[cur][(wi * 64 + ii * 16 + l16) * 32 + quad * 8];
            bfr[ii] = *(const long*)&Bs[cur][(wj * 64 + ii * 16 + l16) * 32 + quad * 8];
        }
        #pragma unroll
        for (int ii = 0; ii < 4; ++ii)
            #pragma unroll
            for (int jj = 0; jj < 4; ++jj)
                acc[ii][jj] = __builtin_amdgcn_mfma_f32_16x16x32_fp8_fp8(af[ii], bfr[jj], acc[ii][jj], 0, 0, 0);
    }

    // Epilogue. C/D layout: col = lane&15, row = quad*4 + reg. out = 1 - acc.
    float* outb = out + (size_t)b * T_DIM * T_DIM;
    #pragma unroll
    for (int ii = 0; ii < 4; ++ii) {
        const int rowbase = ti * 128 + wi * 64 + ii * 16 + quad * 4;
        #pragma unroll
        for (int jj = 0; jj < 4; ++jj) {
            const int col = tj * 128 + wj * 64 + jj * 16 + l16;
            #pragma unroll
            for (int r = 0; r < 4; ++r)
                outb[(size_t)(rowbase + r) * T_DIM + col] = 1.0f - acc[ii][jj][r];
        }
    }
    if (ti != tj) {
        // Mirror tile: each lane's 4 acc values share one col and 4 consecutive
        // rows -> one aligned f32x4 store; 4 quads of same l16 cover a 64B line.
        #pragma unroll
        for (int ii = 0; ii < 4; ++ii) {
            const int rowbase = ti * 128 + wi * 64 + ii * 16 + quad * 4;
            #pragma unroll
            for (int jj = 0; jj < 4; ++jj) {
                const int col = tj * 128 + wj * 64 + jj * 16 + l16;
                f32x4 v;
                v[0] = 1.0f - acc[ii][jj][0];
                v[1] = 1.0f - acc[ii][jj][1];
                v[2] = 1.0f - acc[ii][jj][2];
                v[3] = 1.0f - acc[ii][jj][3];
                *(f32x4*)(outb + (size_t)col * T_DIM + rowbase) = v;
            }
        }
    }
}

extern "C" void kernel_launch(void* const* d_in, const int* in_sizes, int n_in,
                              void* d_out, int out_size, void* d_ws, size_t ws_size,
                              hipStream_t stream) {
    const float* x = (const float*)d_in[0];
    float* out = (float*)d_out;
    uint32_t* metric = (uint32_t*)d_ws;  // 32768 x 768 fp8 = 24 MiB

    normalize_rows_fp8<<<dim3((B_DIM * T_DIM) / 4), dim3(256), 0, stream>>>(x, metric);
    // 1152 blocks, batch-fastest: all 36 tiles of batch b share XCD (b&7).
    gemm_nt_sym_fp8<<<dim3(NTRI * B_DIM), dim3(256), 0, stream>>>((const uint8_t*)metric, out);
}